// Round 6
// baseline (90.538 us; speedup 1.0000x reference)
//
#include <hip/hip_runtime.h>

// Problem constants
constexpr int NB  = 1024;
constexpr int NIN = 512;
constexpr int NJ  = 64;
constexpr int NK  = 8;
constexpr int NC  = NJ * NK;          // 512
constexpr int OUTC = NIN + NJ;        // 576
constexpr float EXPN10 = 4.5399929762484854e-05f;
constexpr float FEAT_BASE = 1024.0f * EXPN10;

typedef __bf16 bf16x8 __attribute__((ext_vector_type(8)));
typedef float floatx16 __attribute__((ext_vector_type(16)));

__device__ __forceinline__ unsigned f2bf(float f) {  // RNE fp32->bf16
  unsigned u = __float_as_uint(f);
  u += 0x7FFFu + ((u >> 16) & 1u);
  return u >> 16;
}

// ---------------------------------------------------------------------------
// Kernel G: fused conv + GEMM + prep + out-init. Grid 16x8 = 128 blocks.
// - Stages fp32 x -> bf16 Xs[row][i] (b128 writes) and fp32 T -> bf16
//   Ts[c][i] transposed via b16 scatter (stride 136 keeps rows 16B-aligned
//   for b128 frag reads; scatter eats ~16-way bank conflicts, ~0.7K cyc).
// - MFMA 32x32x16 bf16, 64x64 tile, BK=128 x 4 chunks.
// - Epilogue: acc -> LDS C-tile -> Mp fp32 [j][b][8], Mb bf16x8, na=|M|^2.
// - Each block also writes its 1/128 slice of out (x copy + FEAT_BASE cols).
// ---------------------------------------------------------------------------
__global__ __launch_bounds__(256) void gemm_fused_kernel(const float* __restrict__ x,
                                                         const float* __restrict__ T,
                                                         float* __restrict__ Mp,
                                                         uint4* __restrict__ Mb,
                                                         float* __restrict__ na,
                                                         float* __restrict__ out) {
  __shared__ __align__(16) ushort smem_u[2 * 64 * 136];   // 34816 B
  ushort* Xs = smem_u;              // [64][136] bf16, row-major (b rows, i cols)
  ushort* Ts = smem_u + 64 * 136;   // [64][136] bf16, transposed (c rows, i cols)
  float*  Cs = (float*)smem_u;      // [64][68] fp32 epilogue tile (17408 B)

  const int tid = threadIdx.x;
  const int b0 = blockIdx.x * 64;
  const int c0 = blockIdx.y * 64;

  const int lane = tid & 63;
  const int w    = tid >> 6;
  const int l31  = lane & 31;
  const int half = lane >> 5;
  const int arow = (w & 1) * 32 + l31;
  const int bcol = (w >> 1) * 32 + l31;

  floatx16 acc = {};

  for (int z = 0; z < 4; ++z) {
    // ---- x-side staging: 64 rows x 128 i, coalesced, b128 LDS writes ----
#pragma unroll
    for (int p = 0; p < 4; ++p) {
      const int u = p * 256 + tid;          // 0..1023
      const int row = u >> 4, seg = u & 15; // seg = 8 floats
      const float* src = &x[(b0 + row) * NIN + z * 128 + seg * 8];
      const float4 v0 = *(const float4*)src;
      const float4 v1 = *(const float4*)(src + 4);
      uint4 pk;
      pk.x = f2bf(v0.x) | (f2bf(v0.y) << 16);
      pk.y = f2bf(v0.z) | (f2bf(v0.w) << 16);
      pk.z = f2bf(v1.x) | (f2bf(v1.y) << 16);
      pk.w = f2bf(v1.z) | (f2bf(v1.w) << 16);
      *(uint4*)&Xs[row * 136 + seg * 8] = pk;
    }
    // ---- T-side staging: 128 i x 64 c, coalesced read, b16 scatter write ----
#pragma unroll
    for (int p = 0; p < 8; ++p) {
      const int u = p * 256 + tid;           // 0..2047
      const int i_loc = u >> 4;              // 0..127
      const int cg    = u & 15;              // 4 c's each
      const float4 v = *(const float4*)&T[(z * 128 + i_loc) * NC + c0 + cg * 4];
      Ts[(cg * 4 + 0) * 136 + i_loc] = (ushort)f2bf(v.x);
      Ts[(cg * 4 + 1) * 136 + i_loc] = (ushort)f2bf(v.y);
      Ts[(cg * 4 + 2) * 136 + i_loc] = (ushort)f2bf(v.z);
      Ts[(cg * 4 + 3) * 136 + i_loc] = (ushort)f2bf(v.w);
    }
    __syncthreads();

#pragma unroll
    for (int s = 0; s < 8; ++s) {
      const bf16x8 af = *(const bf16x8*)&Xs[arow * 136 + s * 16 + half * 8];
      const bf16x8 bf = *(const bf16x8*)&Ts[bcol * 136 + s * 16 + half * 8];
      acc = __builtin_amdgcn_mfma_f32_32x32x16_bf16(af, bf, acc, 0, 0, 0);
    }
    __syncthreads();
  }

  // ---- epilogue: acc -> Cs (stride 68, conflict-free), then prep rows ----
#pragma unroll
  for (int reg = 0; reg < 16; ++reg) {
    const int row = (reg & 3) + 8 * (reg >> 2) + 4 * half;
    Cs[((w & 1) * 32 + row) * 68 + (w >> 1) * 32 + l31] = acc[reg];
  }
  __syncthreads();

#pragma unroll
  for (int pass = 0; pass < 2; ++pass) {
    const int jl = (tid >> 6) + pass * 4;   // 0..7 local j
    const int b  = tid & 63;                // local b
    const float4 m0 = *(const float4*)&Cs[b * 68 + jl * 8];
    const float4 m1 = *(const float4*)&Cs[b * 68 + jl * 8 + 4];
    const int j_g = blockIdx.y * 8 + jl;
    const int idx = j_g * NB + b0 + b;
    ((float4*)Mp)[idx * 2]     = m0;
    ((float4*)Mp)[idx * 2 + 1] = m1;
    float s = m0.x * m0.x;
    s = fmaf(m0.y, m0.y, s); s = fmaf(m0.z, m0.z, s); s = fmaf(m0.w, m0.w, s);
    s = fmaf(m1.x, m1.x, s); s = fmaf(m1.y, m1.y, s); s = fmaf(m1.z, m1.z, s);
    s = fmaf(m1.w, m1.w, s);
    na[idx] = s;
    uint4 pk;
    pk.x = f2bf(m0.x) | (f2bf(m0.y) << 16);
    pk.y = f2bf(m0.z) | (f2bf(m0.w) << 16);
    pk.z = f2bf(m1.x) | (f2bf(m1.y) << 16);
    pk.w = f2bf(m1.z) | (f2bf(m1.w) << 16);
    Mb[idx] = pk;
  }

  // ---- out-init: 128 blocks x 4608 = 589824 = 1024*576 exactly ----
  const int obase = (blockIdx.y * 16 + blockIdx.x) * 4608;
#pragma unroll
  for (int p = 0; p < 18; ++p) {
    const int idx = obase + p * 256 + tid;
    const int b = idx / OUTC;
    const int c = idx - b * OUTC;
    out[idx] = (c < NIN) ? x[b * NIN + c] : FEAT_BASE;
  }
}

// ---------------------------------------------------------------------------
// Kernel P: pairwise via MFMA + exact per-pair prefilter; corrections go
// straight into out[b][512+j] (out pre-initialized with FEAT_BASE by G).
// flag iff 0.995*(na+nb) - 2P < 100 (no false negatives; FP rate ~1e-5).
// ---------------------------------------------------------------------------
__global__ __launch_bounds__(256) void pairwise_kernel(const uint4* __restrict__ Mb,
                                                       const float* __restrict__ na,
                                                       const float* __restrict__ Mp,
                                                       float* __restrict__ out) {
  const int j    = blockIdx.x;
  const int ag   = blockIdx.y;
  const int bh   = blockIdx.z;
  const int tid  = threadIdx.x;
  const int lane = tid & 63;
  const int w    = tid >> 6;
  const int col  = lane & 31;
  const int h    = lane >> 5;
  const int jb   = j * NB;

  __shared__ uint4 Mb_s[513];    // [512] = zeros for K-pad lanes
  __shared__ float nb_s[512];
  __shared__ float na_s[128];

  const int bbeg = bh * 512;
  Mb_s[tid]       = Mb[jb + bbeg + tid];
  Mb_s[tid + 256] = Mb[jb + bbeg + tid + 256];
  nb_s[tid]       = na[jb + bbeg + tid];
  nb_s[tid + 256] = na[jb + bbeg + tid + 256];
  if (tid == 0) Mb_s[512] = uint4{0u, 0u, 0u, 0u};

  const int a0 = ag * 128 + w * 32;
  if (lane < 32) na_s[w * 32 + lane] = na[jb + a0 + lane];

  uint4 araw = uint4{0u, 0u, 0u, 0u};
  if (lane < 32) araw = Mb[jb + a0 + lane];
  const bf16x8 af = __builtin_bit_cast(bf16x8, araw);

  __syncthreads();

  float c995[16];
#pragma unroll
  for (int reg = 0; reg < 16; ++reg) {
    const int row = (reg & 3) + 8 * (reg >> 2) + 4 * h;
    c995[reg] = 0.995f * na_s[w * 32 + row];
  }

  const floatx16 zero = {};

#pragma unroll 2
  for (int bt = 0; bt < 16; ++bt) {
    const int bidx = bt * 32 + col;
    const uint4 braw = Mb_s[lane < 32 ? bidx : 512];
    const bf16x8 bf = __builtin_bit_cast(bf16x8, braw);
    const floatx16 P = __builtin_amdgcn_mfma_f32_32x32x16_bf16(af, bf, zero, 0, 0, 0);
    const float nb_l = nb_s[bidx];
    const float rhs = 100.0f - 0.995f * nb_l;

    float t = fmaf(-2.0f, P[0], c995[0]);
#pragma unroll
    for (int reg = 1; reg < 16; ++reg)
      t = fminf(t, fmaf(-2.0f, P[reg], c995[reg]));

    if (__any(t < rhs)) {   // rare: ~diagonal tiles only
#pragma unroll
      for (int reg = 0; reg < 16; ++reg) {
        if (fmaf(-2.0f, P[reg], c995[reg]) < rhs) {
          const int row = (reg & 3) + 8 * (reg >> 2) + 4 * h;
          const int a = a0 + row;
          const int b = bbeg + bt * 32 + col;
          float corr;
          if (a == b) {
            corr = 1.0f - EXPN10;
          } else {
            const float4 av0 = ((const float4*)Mp)[(jb + a) * 2];
            const float4 av1 = ((const float4*)Mp)[(jb + a) * 2 + 1];
            const float4 bv0 = ((const float4*)Mp)[(jb + b) * 2];
            const float4 bv1 = ((const float4*)Mp)[(jb + b) * 2 + 1];
            float d = av0.x - bv0.x; float sq = d * d;
            d = av0.y - bv0.y; sq = fmaf(d, d, sq);
            d = av0.z - bv0.z; sq = fmaf(d, d, sq);
            d = av0.w - bv0.w; sq = fmaf(d, d, sq);
            d = av1.x - bv1.x; sq = fmaf(d, d, sq);
            d = av1.y - bv1.y; sq = fmaf(d, d, sq);
            d = av1.z - bv1.z; sq = fmaf(d, d, sq);
            d = av1.w - bv1.w; sq = fmaf(d, d, sq);
            const float nrm = sqrtf(sq);
            corr = (nrm < 10.0f) ? (__expf(-nrm) - EXPN10) : 0.0f;
          }
          if (corr != 0.0f) atomicAdd(&out[a * OUTC + NIN + j], corr);
        }
      }
    }
  }
}

// ---------------------------------------------------------------------------
extern "C" void kernel_launch(void* const* d_in, const int* in_sizes, int n_in,
                              void* d_out, int out_size, void* d_ws, size_t ws_size,
                              hipStream_t stream) {
  const float* x = (const float*)d_in[0];
  const float* T = (const float*)d_in[1];
  float* out = (float*)d_out;

  // workspace layout (3.25 MB)
  float* Mp = (float*)d_ws;                       // [64][1024][8] fp32   2 MB
  float* na = Mp + (size_t)NJ * NB * NK;          // [64][1024]         256 KB
  uint4* Mb = (uint4*)(na + (size_t)NJ * NB);     // [64][1024] bf16x8    1 MB

  gemm_fused_kernel<<<dim3(16, 8), 256, 0, stream>>>(x, T, Mp, Mb, na, out);
  pairwise_kernel<<<dim3(NJ, 8, 2), 256, 0, stream>>>(Mb, na, Mp, out);
}

// Round 7
// 85.081 us; speedup vs baseline: 1.0641x; 1.0641x over previous
//
#include <hip/hip_runtime.h>

// Problem constants
constexpr int NB  = 1024;
constexpr int NIN = 512;
constexpr int NJ  = 64;
constexpr int NK  = 8;
constexpr int NC  = NJ * NK;          // 512
constexpr int OUTC = NIN + NJ;        // 576
constexpr float EXPN10 = 4.5399929762484854e-05f;
constexpr float FEAT_BASE = 1024.0f * EXPN10;

typedef __bf16 bf16x8 __attribute__((ext_vector_type(8)));
typedef float floatx16 __attribute__((ext_vector_type(16)));

__device__ __forceinline__ unsigned f2bf(float f) {  // RNE fp32->bf16
  unsigned u = __float_as_uint(f);
  u += 0x7FFFu + ((u >> 16) & 1u);
  return u >> 16;
}

// ---------------------------------------------------------------------------
// Kernel G: fused conv + GEMM + prep. Grid 16x8 = 128 blocks, 4 waves.
// Stages fp32 x -> bf16 Xs (b128 writes) and fp32 T -> bf16 Ts transposed
// (b16 scatter, stride 136 keeps rows 16B-aligned). MFMA 32x32x16 bf16,
// 64x64 tile, BK=128 x 4. Epilogue -> Mp fp32 [j][b][8], Mb bf16x8, na=|M|^2.
// ---------------------------------------------------------------------------
__global__ __launch_bounds__(256) void gemm_fused_kernel(const float* __restrict__ x,
                                                         const float* __restrict__ T,
                                                         float* __restrict__ Mp,
                                                         uint4* __restrict__ Mb,
                                                         float* __restrict__ na) {
  __shared__ __align__(16) ushort smem_u[2 * 64 * 136];   // 34816 B
  ushort* Xs = smem_u;              // [64][136] bf16 (b rows, i cols)
  ushort* Ts = smem_u + 64 * 136;   // [64][136] bf16 transposed (c rows, i cols)
  float*  Cs = (float*)smem_u;      // [64][68] fp32 epilogue tile

  const int tid = threadIdx.x;
  const int b0 = blockIdx.x * 64;
  const int c0 = blockIdx.y * 64;

  const int lane = tid & 63;
  const int w    = tid >> 6;
  const int l31  = lane & 31;
  const int half = lane >> 5;
  const int arow = (w & 1) * 32 + l31;
  const int bcol = (w >> 1) * 32 + l31;

  floatx16 acc = {};

  for (int z = 0; z < 4; ++z) {
    // x-side staging: coalesced float4 reads, bf16 pack, b128 LDS writes
#pragma unroll
    for (int p = 0; p < 4; ++p) {
      const int u = p * 256 + tid;
      const int row = u >> 4, seg = u & 15;
      const float* src = &x[(b0 + row) * NIN + z * 128 + seg * 8];
      const float4 v0 = *(const float4*)src;
      const float4 v1 = *(const float4*)(src + 4);
      uint4 pk;
      pk.x = f2bf(v0.x) | (f2bf(v0.y) << 16);
      pk.y = f2bf(v0.z) | (f2bf(v0.w) << 16);
      pk.z = f2bf(v1.x) | (f2bf(v1.y) << 16);
      pk.w = f2bf(v1.z) | (f2bf(v1.w) << 16);
      *(uint4*)&Xs[row * 136 + seg * 8] = pk;
    }
    // T-side staging: coalesced read, transposed b16 scatter write
#pragma unroll
    for (int p = 0; p < 8; ++p) {
      const int u = p * 256 + tid;
      const int i_loc = u >> 4;
      const int cg    = u & 15;
      const float4 v = *(const float4*)&T[(z * 128 + i_loc) * NC + c0 + cg * 4];
      Ts[(cg * 4 + 0) * 136 + i_loc] = (ushort)f2bf(v.x);
      Ts[(cg * 4 + 1) * 136 + i_loc] = (ushort)f2bf(v.y);
      Ts[(cg * 4 + 2) * 136 + i_loc] = (ushort)f2bf(v.z);
      Ts[(cg * 4 + 3) * 136 + i_loc] = (ushort)f2bf(v.w);
    }
    __syncthreads();

#pragma unroll
    for (int s = 0; s < 8; ++s) {
      const bf16x8 af = *(const bf16x8*)&Xs[arow * 136 + s * 16 + half * 8];
      const bf16x8 bf = *(const bf16x8*)&Ts[bcol * 136 + s * 16 + half * 8];
      acc = __builtin_amdgcn_mfma_f32_32x32x16_bf16(af, bf, acc, 0, 0, 0);
    }
    __syncthreads();
  }

  // epilogue: acc -> Cs (stride 68), then per-(j,b) row emission
#pragma unroll
  for (int reg = 0; reg < 16; ++reg) {
    const int row = (reg & 3) + 8 * (reg >> 2) + 4 * half;
    Cs[((w & 1) * 32 + row) * 68 + (w >> 1) * 32 + l31] = acc[reg];
  }
  __syncthreads();

#pragma unroll
  for (int pass = 0; pass < 2; ++pass) {
    const int jl = (tid >> 6) + pass * 4;
    const int b  = tid & 63;
    const float4 m0 = *(const float4*)&Cs[b * 68 + jl * 8];
    const float4 m1 = *(const float4*)&Cs[b * 68 + jl * 8 + 4];
    const int j_g = blockIdx.y * 8 + jl;
    const int idx = j_g * NB + b0 + b;
    ((float4*)Mp)[idx * 2]     = m0;
    ((float4*)Mp)[idx * 2 + 1] = m1;
    float s = m0.x * m0.x;
    s = fmaf(m0.y, m0.y, s); s = fmaf(m0.z, m0.z, s); s = fmaf(m0.w, m0.w, s);
    s = fmaf(m1.x, m1.x, s); s = fmaf(m1.y, m1.y, s); s = fmaf(m1.z, m1.z, s);
    s = fmaf(m1.w, m1.w, s);
    na[idx] = s;
    uint4 pk;
    pk.x = f2bf(m0.x) | (f2bf(m0.y) << 16);
    pk.y = f2bf(m0.z) | (f2bf(m0.w) << 16);
    pk.z = f2bf(m1.x) | (f2bf(m1.y) << 16);
    pk.w = f2bf(m1.z) | (f2bf(m1.w) << 16);
    Mb[idx] = pk;
  }
}

// ---------------------------------------------------------------------------
// Kernel P': pairwise, atomic-free output ownership.
// Grid (64 j, 8 ag) = 512 blocks; block owns (all b) x (128 a-rows) x (one j):
// - corrections accumulate in LDS feats_s[128] (rare; ~1 diagonal hit/row)
// - final store: out[a][512+j] = FEAT_BASE + feats_s  (single owner, no races)
// - block also copies 2 rows of out[b][0:512] from x (disjoint ownership)
// Prefilter: flag iff 0.995*(na+nb) - 2P < 100 (no false negatives, FP~1e-5).
// ---------------------------------------------------------------------------
__global__ __launch_bounds__(256) void pairwise_kernel(const uint4* __restrict__ Mb,
                                                       const float* __restrict__ na,
                                                       const float* __restrict__ Mp,
                                                       const float* __restrict__ x,
                                                       float* __restrict__ out) {
  const int j    = blockIdx.x;
  const int ag   = blockIdx.y;
  const int tid  = threadIdx.x;
  const int lane = tid & 63;
  const int w    = tid >> 6;
  const int col  = lane & 31;
  const int h    = lane >> 5;
  const int jb   = j * NB;

  __shared__ uint4 Mb_s[1025];   // [1024] = zeros for K-pad lanes (16.4 KB)
  __shared__ float nb_s[1024];
  __shared__ float na_s[128];
  __shared__ float feats_s[128];

  // ---- x-copy: block owns out rows 2*bid..2*bid+1, cols [0,512) ----
  {
    const int bid = j * 8 + ag;              // 0..511
    const int r = bid * 2 + (tid >> 7);      // row 0..1023
    const int c4 = (tid & 127) * 4;
    *(float4*)&out[r * OUTC + c4] = *(const float4*)&x[r * NIN + c4];
  }

  // ---- stage all 1024 b rows ----
#pragma unroll
  for (int p = 0; p < 4; ++p) {
    Mb_s[p * 256 + tid] = Mb[jb + p * 256 + tid];
    nb_s[p * 256 + tid] = na[jb + p * 256 + tid];
  }
  if (tid == 0) Mb_s[1024] = uint4{0u, 0u, 0u, 0u};
  if (tid < 128) feats_s[tid] = 0.0f;

  const int a0 = ag * 128 + w * 32;
  if (lane < 32) na_s[w * 32 + lane] = na[jb + a0 + lane];

  uint4 araw = uint4{0u, 0u, 0u, 0u};
  if (lane < 32) araw = Mb[jb + a0 + lane];
  const bf16x8 af = __builtin_bit_cast(bf16x8, araw);

  __syncthreads();

  float c995[16];
#pragma unroll
  for (int reg = 0; reg < 16; ++reg) {
    const int row = (reg & 3) + 8 * (reg >> 2) + 4 * h;
    c995[reg] = 0.995f * na_s[w * 32 + row];
  }

  const floatx16 zero = {};

#pragma unroll 2
  for (int bt = 0; bt < 32; ++bt) {
    const int bidx = bt * 32 + col;
    const uint4 braw = Mb_s[lane < 32 ? bidx : 1024];
    const bf16x8 bf = __builtin_bit_cast(bf16x8, braw);
    const floatx16 P = __builtin_amdgcn_mfma_f32_32x32x16_bf16(af, bf, zero, 0, 0, 0);
    const float nb_l = nb_s[bidx];
    const float rhs = 100.0f - 0.995f * nb_l;

    float t = fmaf(-2.0f, P[0], c995[0]);
#pragma unroll
    for (int reg = 1; reg < 16; ++reg)
      t = fminf(t, fmaf(-2.0f, P[reg], c995[reg]));

    if (__any(t < rhs)) {   // rare: ~diagonal tiles only
#pragma unroll
      for (int reg = 0; reg < 16; ++reg) {
        if (fmaf(-2.0f, P[reg], c995[reg]) < rhs) {
          const int row = (reg & 3) + 8 * (reg >> 2) + 4 * h;
          const int a = a0 + row;
          const int b = bt * 32 + col;
          float corr;
          if (a == b) {
            corr = 1.0f - EXPN10;
          } else {
            const float4 av0 = ((const float4*)Mp)[(jb + a) * 2];
            const float4 av1 = ((const float4*)Mp)[(jb + a) * 2 + 1];
            const float4 bv0 = ((const float4*)Mp)[(jb + b) * 2];
            const float4 bv1 = ((const float4*)Mp)[(jb + b) * 2 + 1];
            float d = av0.x - bv0.x; float sq = d * d;
            d = av0.y - bv0.y; sq = fmaf(d, d, sq);
            d = av0.z - bv0.z; sq = fmaf(d, d, sq);
            d = av0.w - bv0.w; sq = fmaf(d, d, sq);
            d = av1.x - bv1.x; sq = fmaf(d, d, sq);
            d = av1.y - bv1.y; sq = fmaf(d, d, sq);
            d = av1.z - bv1.z; sq = fmaf(d, d, sq);
            d = av1.w - bv1.w; sq = fmaf(d, d, sq);
            const float nrm = sqrtf(sq);
            corr = (nrm < 10.0f) ? (__expf(-nrm) - EXPN10) : 0.0f;
          }
          if (corr != 0.0f) atomicAdd(&feats_s[w * 32 + row], corr);  // LDS atomic
        }
      }
    }
  }

  __syncthreads();
  // ---- owned store: out[a][512+j], a = ag*128 + t, t in [0,128) ----
  if (tid < 128)
    out[(ag * 128 + tid) * OUTC + NIN + j] = FEAT_BASE + feats_s[tid];
}

// ---------------------------------------------------------------------------
extern "C" void kernel_launch(void* const* d_in, const int* in_sizes, int n_in,
                              void* d_out, int out_size, void* d_ws, size_t ws_size,
                              hipStream_t stream) {
  const float* x = (const float*)d_in[0];
  const float* T = (const float*)d_in[1];
  float* out = (float*)d_out;

  // workspace layout (3.25 MB)
  float* Mp = (float*)d_ws;                       // [64][1024][8] fp32   2 MB
  float* na = Mp + (size_t)NJ * NB * NK;          // [64][1024]         256 KB
  uint4* Mb = (uint4*)(na + (size_t)NJ * NB);     // [64][1024] bf16x8    1 MB

  gemm_fused_kernel<<<dim3(16, 8), 256, 0, stream>>>(x, T, Mp, Mb, na);
  pairwise_kernel<<<dim3(NJ, 8), 256, 0, stream>>>(Mb, na, Mp, x, out);
}

// Round 8
// 75.885 us; speedup vs baseline: 1.1931x; 1.1212x over previous
//
#include <hip/hip_runtime.h>

// Problem constants
constexpr int NB  = 1024;
constexpr int NIN = 512;
constexpr int NJ  = 64;
constexpr int NK  = 8;
constexpr int NC  = NJ * NK;          // 512
constexpr int OUTC = NIN + NJ;        // 576
constexpr float EXPN10 = 4.5399929762484854e-05f;
constexpr float FEAT_BASE = 1024.0f * EXPN10;

typedef __bf16 bf16x8 __attribute__((ext_vector_type(8)));
typedef float floatx16 __attribute__((ext_vector_type(16)));

__device__ __forceinline__ unsigned f2bf(float f) {  // RNE fp32->bf16
  unsigned u = __float_as_uint(f);
  u += 0x7FFFu + ((u >> 16) & 1u);
  return u >> 16;
}

// ---------------------------------------------------------------------------
// Kernel 1 (fused): role-switched on blockIdx.x
//   [0,256)    : x fp32 -> xb bf16
//   [256,320)  : T fp32 [i][c] -> Tt bf16 [c][i] (64x64 LDS transpose tiles)
//   [320,2624) : out init — out[b][0:512]=x[b], out[b][512:576]=FEAT_BASE
// ---------------------------------------------------------------------------
__global__ __launch_bounds__(256) void conv_init_kernel(const float* __restrict__ x,
                                                        const float* __restrict__ T,
                                                        uint4* __restrict__ xb,
                                                        ushort* __restrict__ Tt,
                                                        float* __restrict__ out) {
  __shared__ float Ts[64][65];
  const int bid = blockIdx.x;
  const int tid = threadIdx.x;

  if (bid < 256) {              // ---- conv_x ----
    const int idx = bid * 256 + tid;            // 0..65535
    const float4 v0 = ((const float4*)x)[idx * 2];
    const float4 v1 = ((const float4*)x)[idx * 2 + 1];
    uint4 p;
    p.x = f2bf(v0.x) | (f2bf(v0.y) << 16);
    p.y = f2bf(v0.z) | (f2bf(v0.w) << 16);
    p.z = f2bf(v1.x) | (f2bf(v1.y) << 16);
    p.w = f2bf(v1.z) | (f2bf(v1.w) << 16);
    xb[idx] = p;
  } else if (bid < 320) {       // ---- conv_T (transpose + bf16) ----
    const int t = bid - 256;
    const int i0 = (t & 7) * 64;
    const int c0 = (t >> 3) * 64;

    const int ti4 = (tid >> 4) * 4;
    const int tc  = (tid & 15) * 4;
#pragma unroll
    for (int r = 0; r < 4; ++r) {
      const float4 v = *(const float4*)&T[(i0 + ti4 + r) * NC + c0 + tc];
      Ts[tc + 0][ti4 + r] = v.x;
      Ts[tc + 1][ti4 + r] = v.y;
      Ts[tc + 2][ti4 + r] = v.z;
      Ts[tc + 3][ti4 + r] = v.w;
    }
    __syncthreads();

    const int co = tid >> 2;
    const int io = (tid & 3) * 16;
    unsigned w[8];
#pragma unroll
    for (int q = 0; q < 8; ++q)
      w[q] = f2bf(Ts[co][io + 2 * q]) | (f2bf(Ts[co][io + 2 * q + 1]) << 16);
    uint4* dst = (uint4*)&Tt[(size_t)(c0 + co) * NIN + i0 + io];
    dst[0] = uint4{w[0], w[1], w[2], w[3]};
    dst[1] = uint4{w[4], w[5], w[6], w[7]};
  } else {                      // ---- out init ----
    const int idx = (bid - 320) * 256 + tid;    // 0..589823
    const int b = idx / OUTC;
    const int c = idx - b * OUTC;
    out[idx] = (c < NIN) ? x[b * NIN + c] : FEAT_BASE;
  }
}

// ---------------------------------------------------------------------------
// Kernel 2: gemm, full K=512, 128 blocks (16 b-tiles x 8 c-tiles), 4 waves.
// Block tile 64x64, BK=128 (4 chunks). MFMA 32x32x16 bf16.
// Writes Mp[j][b][k] directly (32B-granule scatter, L2-absorbed).
// ---------------------------------------------------------------------------
__global__ __launch_bounds__(256) void gemm_kernel(const uint4* __restrict__ xb,
                                                   const uint4* __restrict__ ttb,
                                                   float* __restrict__ Mp) {
  __shared__ __align__(16) __bf16 Xs[64 * 136];
  __shared__ __align__(16) __bf16 Ts[64 * 136];

  const int tid = threadIdx.x;
  const int b0 = blockIdx.x * 64;
  const int c0 = blockIdx.y * 64;

  const int lane = tid & 63;
  const int w    = tid >> 6;
  const int l31  = lane & 31;
  const int half = lane >> 5;
  const int arow = (w & 1) * 32 + l31;
  const int bcol = (w >> 1) * 32 + l31;

  floatx16 acc = {};

  for (int z = 0; z < 4; ++z) {
#pragma unroll
    for (int t = 0; t < 4; ++t) {
      const int u = t * 256 + tid;
      const int row = u >> 4, seg = u & 15;
      *(uint4*)&Xs[row * 136 + seg * 8] = xb[(b0 + row) * 64 + z * 16 + seg];
      *(uint4*)&Ts[row * 136 + seg * 8] = ttb[(c0 + row) * 64 + z * 16 + seg];
    }
    __syncthreads();

#pragma unroll
    for (int s = 0; s < 8; ++s) {
      const bf16x8 af = *(const bf16x8*)&Xs[arow * 136 + s * 16 + half * 8];
      const bf16x8 bf = *(const bf16x8*)&Ts[bcol * 136 + s * 16 + half * 8];
      acc = __builtin_amdgcn_mfma_f32_32x32x16_bf16(af, bf, acc, 0, 0, 0);
    }
    __syncthreads();
  }

#pragma unroll
  for (int reg = 0; reg < 16; ++reg) {
    const int row = (reg & 3) + 8 * (reg >> 2) + 4 * half;
    const int b = b0 + (w & 1) * 32 + row;
    const int c = c0 + (w >> 1) * 32 + l31;
    Mp[((c >> 3) * NB + b) * NK + (c & 7)] = acc[reg];
  }
}

// ---------------------------------------------------------------------------
// Kernel 3: prep — Mb bf16x8 + na = |M|^2 from Mp (all coalesced, 3.25 MB)
// ---------------------------------------------------------------------------
__global__ __launch_bounds__(256) void prep_kernel(const float* __restrict__ Mp,
                                                   uint4* __restrict__ Mb,
                                                   float* __restrict__ na) {
  const int idx = blockIdx.x * 256 + threadIdx.x;   // j*1024+b
  const float4 m0 = ((const float4*)Mp)[idx * 2];
  const float4 m1 = ((const float4*)Mp)[idx * 2 + 1];
  float s = m0.x * m0.x;
  s = fmaf(m0.y, m0.y, s); s = fmaf(m0.z, m0.z, s); s = fmaf(m0.w, m0.w, s);
  s = fmaf(m1.x, m1.x, s); s = fmaf(m1.y, m1.y, s); s = fmaf(m1.z, m1.z, s);
  s = fmaf(m1.w, m1.w, s);
  na[idx] = s;
  uint4 p;
  p.x = f2bf(m0.x) | (f2bf(m0.y) << 16);
  p.y = f2bf(m0.z) | (f2bf(m0.w) << 16);
  p.z = f2bf(m1.x) | (f2bf(m1.y) << 16);
  p.w = f2bf(m1.z) | (f2bf(m1.w) << 16);
  Mb[idx] = p;
}

// ---------------------------------------------------------------------------
// Kernel 4: pairwise via MFMA + exact per-pair prefilter; corrections go
// straight into out[b][512+j] (out pre-initialized with FEAT_BASE).
// flag iff 0.995*(na+nb) - 2P < 100 (no false negatives; FP rate ~1e-5).
// ---------------------------------------------------------------------------
__global__ __launch_bounds__(256) void pairwise_kernel(const uint4* __restrict__ Mb,
                                                       const float* __restrict__ na,
                                                       const float* __restrict__ Mp,
                                                       float* __restrict__ out) {
  const int j    = blockIdx.x;
  const int ag   = blockIdx.y;
  const int bh   = blockIdx.z;
  const int tid  = threadIdx.x;
  const int lane = tid & 63;
  const int w    = tid >> 6;
  const int col  = lane & 31;
  const int h    = lane >> 5;
  const int jb   = j * NB;

  __shared__ uint4 Mb_s[513];    // [512] = zeros for K-pad lanes
  __shared__ float nb_s[512];
  __shared__ float na_s[128];

  const int bbeg = bh * 512;
  Mb_s[tid]       = Mb[jb + bbeg + tid];
  Mb_s[tid + 256] = Mb[jb + bbeg + tid + 256];
  nb_s[tid]       = na[jb + bbeg + tid];
  nb_s[tid + 256] = na[jb + bbeg + tid + 256];
  if (tid == 0) Mb_s[512] = uint4{0u, 0u, 0u, 0u};

  const int a0 = ag * 128 + w * 32;
  if (lane < 32) na_s[w * 32 + lane] = na[jb + a0 + lane];

  uint4 araw = uint4{0u, 0u, 0u, 0u};
  if (lane < 32) araw = Mb[jb + a0 + lane];
  const bf16x8 af = __builtin_bit_cast(bf16x8, araw);

  __syncthreads();

  float c995[16];
#pragma unroll
  for (int reg = 0; reg < 16; ++reg) {
    const int row = (reg & 3) + 8 * (reg >> 2) + 4 * h;
    c995[reg] = 0.995f * na_s[w * 32 + row];
  }

  const floatx16 zero = {};

#pragma unroll 2
  for (int bt = 0; bt < 16; ++bt) {
    const int bidx = bt * 32 + col;
    const uint4 braw = Mb_s[lane < 32 ? bidx : 512];
    const bf16x8 bf = __builtin_bit_cast(bf16x8, braw);
    const floatx16 P = __builtin_amdgcn_mfma_f32_32x32x16_bf16(af, bf, zero, 0, 0, 0);
    const float nb_l = nb_s[bidx];
    const float rhs = 100.0f - 0.995f * nb_l;

    float t = fmaf(-2.0f, P[0], c995[0]);
#pragma unroll
    for (int reg = 1; reg < 16; ++reg)
      t = fminf(t, fmaf(-2.0f, P[reg], c995[reg]));

    if (__any(t < rhs)) {   // rare: ~diagonal tiles only
#pragma unroll
      for (int reg = 0; reg < 16; ++reg) {
        if (fmaf(-2.0f, P[reg], c995[reg]) < rhs) {
          const int row = (reg & 3) + 8 * (reg >> 2) + 4 * h;
          const int a = a0 + row;
          const int b = bbeg + bt * 32 + col;
          float corr;
          if (a == b) {
            corr = 1.0f - EXPN10;
          } else {
            const float4 av0 = ((const float4*)Mp)[(jb + a) * 2];
            const float4 av1 = ((const float4*)Mp)[(jb + a) * 2 + 1];
            const float4 bv0 = ((const float4*)Mp)[(jb + b) * 2];
            const float4 bv1 = ((const float4*)Mp)[(jb + b) * 2 + 1];
            float d = av0.x - bv0.x; float sq = d * d;
            d = av0.y - bv0.y; sq = fmaf(d, d, sq);
            d = av0.z - bv0.z; sq = fmaf(d, d, sq);
            d = av0.w - bv0.w; sq = fmaf(d, d, sq);
            d = av1.x - bv1.x; sq = fmaf(d, d, sq);
            d = av1.y - bv1.y; sq = fmaf(d, d, sq);
            d = av1.z - bv1.z; sq = fmaf(d, d, sq);
            d = av1.w - bv1.w; sq = fmaf(d, d, sq);
            const float nrm = sqrtf(sq);
            corr = (nrm < 10.0f) ? (__expf(-nrm) - EXPN10) : 0.0f;
          }
          if (corr != 0.0f) atomicAdd(&out[a * OUTC + NIN + j], corr);
        }
      }
    }
  }
}

// ---------------------------------------------------------------------------
extern "C" void kernel_launch(void* const* d_in, const int* in_sizes, int n_in,
                              void* d_out, int out_size, void* d_ws, size_t ws_size,
                              hipStream_t stream) {
  const float* x = (const float*)d_in[0];
  const float* T = (const float*)d_in[1];
  float* out = (float*)d_out;

  // workspace layout (4.75 MB)
  float* Mp  = (float*)d_ws;                         // [64][1024][8] fp32   2 MB
  float* na  = Mp + (size_t)NJ * NB * NK;            // [64][1024]         256 KB
  uint4* Mb  = (uint4*)(na + (size_t)NJ * NB);       // [64][1024] bf16x8    1 MB
  uint4* xb  = Mb + (size_t)NJ * NB;                 // [1024][512] bf16     1 MB
  ushort* Tt = (ushort*)(xb + (size_t)NB * NIN / 8); // [512][512] bf16    0.5 MB

  conv_init_kernel<<<dim3(2624), 256, 0, stream>>>(x, T, xb, Tt, out);
  gemm_kernel<<<dim3(16, 8), 256, 0, stream>>>(xb, (const uint4*)Tt, Mp);
  prep_kernel<<<dim3(256), 256, 0, stream>>>(Mp, Mb, na);
  pairwise_kernel<<<dim3(NJ, 8, 2), 256, 0, stream>>>(Mb, na, Mp, out);
}

// Round 9
// 73.654 us; speedup vs baseline: 1.2292x; 1.0303x over previous
//
#include <hip/hip_runtime.h>

// Problem constants
constexpr int NB  = 1024;
constexpr int NIN = 512;
constexpr int NJ  = 64;
constexpr int NK  = 8;
constexpr int NC  = NJ * NK;          // 512
constexpr int OUTC = NIN + NJ;        // 576
constexpr float EXPN10 = 4.5399929762484854e-05f;
constexpr float FEAT_BASE = 1024.0f * EXPN10;

typedef __bf16 bf16x8 __attribute__((ext_vector_type(8)));
typedef float floatx16 __attribute__((ext_vector_type(16)));

__device__ __forceinline__ unsigned f2bf(float f) {  // RNE fp32->bf16
  unsigned u = __float_as_uint(f);
  u += 0x7FFFu + ((u >> 16) & 1u);
  return u >> 16;
}

// ---------------------------------------------------------------------------
// Kernel 1 (fused): role-switched on blockIdx.x
//   [0,256)    : x fp32 -> xb bf16
//   [256,320)  : T fp32 [i][c] -> Tt bf16 [c][i] (64x64 LDS transpose tiles)
//   [320,2624) : out init — out[b][0:512]=x[b], out[b][512:576]=FEAT_BASE
// (unchanged from R5/R8 — proven fast)
// ---------------------------------------------------------------------------
__global__ __launch_bounds__(256) void conv_init_kernel(const float* __restrict__ x,
                                                        const float* __restrict__ T,
                                                        uint4* __restrict__ xb,
                                                        ushort* __restrict__ Tt,
                                                        float* __restrict__ out) {
  __shared__ float Ts[64][65];
  const int bid = blockIdx.x;
  const int tid = threadIdx.x;

  if (bid < 256) {              // ---- conv_x ----
    const int idx = bid * 256 + tid;            // 0..65535
    const float4 v0 = ((const float4*)x)[idx * 2];
    const float4 v1 = ((const float4*)x)[idx * 2 + 1];
    uint4 p;
    p.x = f2bf(v0.x) | (f2bf(v0.y) << 16);
    p.y = f2bf(v0.z) | (f2bf(v0.w) << 16);
    p.z = f2bf(v1.x) | (f2bf(v1.y) << 16);
    p.w = f2bf(v1.z) | (f2bf(v1.w) << 16);
    xb[idx] = p;
  } else if (bid < 320) {       // ---- conv_T (transpose + bf16) ----
    const int t = bid - 256;
    const int i0 = (t & 7) * 64;
    const int c0 = (t >> 3) * 64;

    const int ti4 = (tid >> 4) * 4;
    const int tc  = (tid & 15) * 4;
#pragma unroll
    for (int r = 0; r < 4; ++r) {
      const float4 v = *(const float4*)&T[(i0 + ti4 + r) * NC + c0 + tc];
      Ts[tc + 0][ti4 + r] = v.x;
      Ts[tc + 1][ti4 + r] = v.y;
      Ts[tc + 2][ti4 + r] = v.z;
      Ts[tc + 3][ti4 + r] = v.w;
    }
    __syncthreads();

    const int co = tid >> 2;
    const int io = (tid & 3) * 16;
    unsigned w[8];
#pragma unroll
    for (int q = 0; q < 8; ++q)
      w[q] = f2bf(Ts[co][io + 2 * q]) | (f2bf(Ts[co][io + 2 * q + 1]) << 16);
    uint4* dst = (uint4*)&Tt[(size_t)(c0 + co) * NIN + i0 + io];
    dst[0] = uint4{w[0], w[1], w[2], w[3]};
    dst[1] = uint4{w[4], w[5], w[6], w[7]};
  } else {                      // ---- out init ----
    const int idx = (bid - 320) * 256 + tid;    // 0..589823
    const int b = idx / OUTC;
    const int c = idx - b * OUTC;
    out[idx] = (c < NIN) ? x[b * NIN + c] : FEAT_BASE;
  }
}

// ---------------------------------------------------------------------------
// Kernel 2: gemm + prep fused. Grid 16x8 = 128 blocks, 4 waves.
// Staging/K-loop identical to R8 (pre-converted bf16 inputs, b128 LDS, MFMA
// 32x32x16). Epilogue (R6-proven): acc -> LDS C-tile (stride 68) -> coalesced
// per-(j,b)-row emission of Mp fp32, Mb bf16x8, na=|M|^2. Replaces both the
// scattered Mp store and the separate prep dispatch.
// ---------------------------------------------------------------------------
__global__ __launch_bounds__(256) void gemm_kernel(const uint4* __restrict__ xb,
                                                   const uint4* __restrict__ ttb,
                                                   float* __restrict__ Mp,
                                                   uint4* __restrict__ Mb,
                                                   float* __restrict__ na) {
  __shared__ __align__(16) ushort smem_u[2 * 64 * 136];   // 34816 B
  ushort* Xs = smem_u;              // [64][136] bf16
  ushort* Ts = smem_u + 64 * 136;   // [64][136] bf16
  float*  Cs = (float*)smem_u;      // [64][68] fp32 epilogue tile (17408 B)

  const int tid = threadIdx.x;
  const int b0 = blockIdx.x * 64;
  const int c0 = blockIdx.y * 64;

  const int lane = tid & 63;
  const int w    = tid >> 6;
  const int l31  = lane & 31;
  const int half = lane >> 5;
  const int arow = (w & 1) * 32 + l31;
  const int bcol = (w >> 1) * 32 + l31;

  floatx16 acc = {};

  for (int z = 0; z < 4; ++z) {
#pragma unroll
    for (int t = 0; t < 4; ++t) {
      const int u = t * 256 + tid;
      const int row = u >> 4, seg = u & 15;
      *(uint4*)&Xs[row * 136 + seg * 8] = xb[(b0 + row) * 64 + z * 16 + seg];
      *(uint4*)&Ts[row * 136 + seg * 8] = ttb[(c0 + row) * 64 + z * 16 + seg];
    }
    __syncthreads();

#pragma unroll
    for (int s = 0; s < 8; ++s) {
      const bf16x8 af = *(const bf16x8*)&Xs[arow * 136 + s * 16 + half * 8];
      const bf16x8 bf = *(const bf16x8*)&Ts[bcol * 136 + s * 16 + half * 8];
      acc = __builtin_amdgcn_mfma_f32_32x32x16_bf16(af, bf, acc, 0, 0, 0);
    }
    __syncthreads();
  }

  // ---- epilogue: acc -> Cs (stride 68, conflict-free), then prep rows ----
#pragma unroll
  for (int reg = 0; reg < 16; ++reg) {
    const int row = (reg & 3) + 8 * (reg >> 2) + 4 * half;
    Cs[((w & 1) * 32 + row) * 68 + (w >> 1) * 32 + l31] = acc[reg];
  }
  __syncthreads();

#pragma unroll
  for (int pass = 0; pass < 2; ++pass) {
    const int jl = (tid >> 6) + pass * 4;   // local j 0..7
    const int b  = tid & 63;                // local b
    const float4 m0 = *(const float4*)&Cs[b * 68 + jl * 8];
    const float4 m1 = *(const float4*)&Cs[b * 68 + jl * 8 + 4];
    const int j_g = blockIdx.y * 8 + jl;
    const int idx = j_g * NB + b0 + b;
    ((float4*)Mp)[idx * 2]     = m0;
    ((float4*)Mp)[idx * 2 + 1] = m1;
    float s = m0.x * m0.x;
    s = fmaf(m0.y, m0.y, s); s = fmaf(m0.z, m0.z, s); s = fmaf(m0.w, m0.w, s);
    s = fmaf(m1.x, m1.x, s); s = fmaf(m1.y, m1.y, s); s = fmaf(m1.z, m1.z, s);
    s = fmaf(m1.w, m1.w, s);
    na[idx] = s;
    uint4 pk;
    pk.x = f2bf(m0.x) | (f2bf(m0.y) << 16);
    pk.y = f2bf(m0.z) | (f2bf(m0.w) << 16);
    pk.z = f2bf(m1.x) | (f2bf(m1.y) << 16);
    pk.w = f2bf(m1.z) | (f2bf(m1.w) << 16);
    Mb[idx] = pk;
  }
}

// ---------------------------------------------------------------------------
// Kernel 3: pairwise via MFMA + exact per-pair prefilter; corrections go
// straight into out[b][512+j] (out pre-initialized with FEAT_BASE).
// flag iff 0.995*(na+nb) - 2P < 100 (no false negatives; FP rate ~1e-5).
// (unchanged from R5/R8 — proven fast)
// ---------------------------------------------------------------------------
__global__ __launch_bounds__(256) void pairwise_kernel(const uint4* __restrict__ Mb,
                                                       const float* __restrict__ na,
                                                       const float* __restrict__ Mp,
                                                       float* __restrict__ out) {
  const int j    = blockIdx.x;
  const int ag   = blockIdx.y;
  const int bh   = blockIdx.z;
  const int tid  = threadIdx.x;
  const int lane = tid & 63;
  const int w    = tid >> 6;
  const int col  = lane & 31;
  const int h    = lane >> 5;
  const int jb   = j * NB;

  __shared__ uint4 Mb_s[513];    // [512] = zeros for K-pad lanes
  __shared__ float nb_s[512];
  __shared__ float na_s[128];

  const int bbeg = bh * 512;
  Mb_s[tid]       = Mb[jb + bbeg + tid];
  Mb_s[tid + 256] = Mb[jb + bbeg + tid + 256];
  nb_s[tid]       = na[jb + bbeg + tid];
  nb_s[tid + 256] = na[jb + bbeg + tid + 256];
  if (tid == 0) Mb_s[512] = uint4{0u, 0u, 0u, 0u};

  const int a0 = ag * 128 + w * 32;
  if (lane < 32) na_s[w * 32 + lane] = na[jb + a0 + lane];

  uint4 araw = uint4{0u, 0u, 0u, 0u};
  if (lane < 32) araw = Mb[jb + a0 + lane];
  const bf16x8 af = __builtin_bit_cast(bf16x8, araw);

  __syncthreads();

  float c995[16];
#pragma unroll
  for (int reg = 0; reg < 16; ++reg) {
    const int row = (reg & 3) + 8 * (reg >> 2) + 4 * h;
    c995[reg] = 0.995f * na_s[w * 32 + row];
  }

  const floatx16 zero = {};

#pragma unroll 2
  for (int bt = 0; bt < 16; ++bt) {
    const int bidx = bt * 32 + col;
    const uint4 braw = Mb_s[lane < 32 ? bidx : 512];
    const bf16x8 bf = __builtin_bit_cast(bf16x8, braw);
    const floatx16 P = __builtin_amdgcn_mfma_f32_32x32x16_bf16(af, bf, zero, 0, 0, 0);
    const float nb_l = nb_s[bidx];
    const float rhs = 100.0f - 0.995f * nb_l;

    float t = fmaf(-2.0f, P[0], c995[0]);
#pragma unroll
    for (int reg = 1; reg < 16; ++reg)
      t = fminf(t, fmaf(-2.0f, P[reg], c995[reg]));

    if (__any(t < rhs)) {   // rare: ~diagonal tiles only
#pragma unroll
      for (int reg = 0; reg < 16; ++reg) {
        if (fmaf(-2.0f, P[reg], c995[reg]) < rhs) {
          const int row = (reg & 3) + 8 * (reg >> 2) + 4 * h;
          const int a = a0 + row;
          const int b = bbeg + bt * 32 + col;
          float corr;
          if (a == b) {
            corr = 1.0f - EXPN10;
          } else {
            const float4 av0 = ((const float4*)Mp)[(jb + a) * 2];
            const float4 av1 = ((const float4*)Mp)[(jb + a) * 2 + 1];
            const float4 bv0 = ((const float4*)Mp)[(jb + b) * 2];
            const float4 bv1 = ((const float4*)Mp)[(jb + b) * 2 + 1];
            float d = av0.x - bv0.x; float sq = d * d;
            d = av0.y - bv0.y; sq = fmaf(d, d, sq);
            d = av0.z - bv0.z; sq = fmaf(d, d, sq);
            d = av0.w - bv0.w; sq = fmaf(d, d, sq);
            d = av1.x - bv1.x; sq = fmaf(d, d, sq);
            d = av1.y - bv1.y; sq = fmaf(d, d, sq);
            d = av1.z - bv1.z; sq = fmaf(d, d, sq);
            d = av1.w - bv1.w; sq = fmaf(d, d, sq);
            const float nrm = sqrtf(sq);
            corr = (nrm < 10.0f) ? (__expf(-nrm) - EXPN10) : 0.0f;
          }
          if (corr != 0.0f) atomicAdd(&out[a * OUTC + NIN + j], corr);
        }
      }
    }
  }
}

// ---------------------------------------------------------------------------
extern "C" void kernel_launch(void* const* d_in, const int* in_sizes, int n_in,
                              void* d_out, int out_size, void* d_ws, size_t ws_size,
                              hipStream_t stream) {
  const float* x = (const float*)d_in[0];
  const float* T = (const float*)d_in[1];
  float* out = (float*)d_out;

  // workspace layout (4.75 MB)
  float* Mp  = (float*)d_ws;                         // [64][1024][8] fp32   2 MB
  float* na  = Mp + (size_t)NJ * NB * NK;            // [64][1024]         256 KB
  uint4* Mb  = (uint4*)(na + (size_t)NJ * NB);       // [64][1024] bf16x8    1 MB
  uint4* xb  = Mb + (size_t)NJ * NB;                 // [1024][512] bf16     1 MB
  ushort* Tt = (ushort*)(xb + (size_t)NB * NIN / 8); // [512][512] bf16    0.5 MB

  conv_init_kernel<<<dim3(2624), 256, 0, stream>>>(x, T, xb, Tt, out);
  gemm_kernel<<<dim3(16, 8), 256, 0, stream>>>(xb, (const uint4*)Tt, Mp, Mb, na);
  pairwise_kernel<<<dim3(NJ, 8, 2), 256, 0, stream>>>(Mb, na, Mp, out);
}